// Round 9
// baseline (389.909 us; speedup 1.0000x reference)
//
#include <hip/hip_runtime.h>
#include <hip/hip_bf16.h>

#define D 768
#define NE 64
#define BSZ 32
#define SEQ 512
#define NREL 7
#define NPAIR 131072
#define NEB 6

typedef __attribute__((ext_vector_type(8))) short short8;
typedef __attribute__((ext_vector_type(4))) float floatx4;

__device__ __forceinline__ short f2bf(float x) {
  union { __hip_bfloat16 b; short s; } u;
  u.b = __float2bfloat16(x);
  return u.s;
}

__device__ __forceinline__ void gl_lds16(const void* g, void* l) {
  __builtin_amdgcn_global_load_lds(
      (const __attribute__((address_space(1))) void*)g,
      (__attribute__((address_space(3))) void*)l, 16, 0, 0);
}

// ---- convert weights f32 -> bf16 (wq, wk, ln1) ----
__global__ void __launch_bounds__(256) k_convert(const float* wq, const float* wk, const float* ln1,
                                                 short* owq, short* owk, short* oln1) {
  int idx = (blockIdx.x * 256 + threadIdx.x) * 4;
  if (idx >= D * D) return;
  float4 a = *(const float4*)(wq + idx);
  float4 b = *(const float4*)(wk + idx);
  float4 c = *(const float4*)(ln1 + idx);
  owq[idx + 0] = f2bf(a.x); owq[idx + 1] = f2bf(a.y); owq[idx + 2] = f2bf(a.z); owq[idx + 3] = f2bf(a.w);
  owk[idx + 0] = f2bf(b.x); owk[idx + 1] = f2bf(b.y); owk[idx + 2] = f2bf(b.z); owk[idx + 3] = f2bf(b.w);
  oln1[idx + 0] = f2bf(c.x); oln1[idx + 1] = f2bf(c.y); oln1[idx + 2] = f2bf(c.z); oln1[idx + 3] = f2bf(c.w);
}

// ---- span mean-pool -> masked bf16 ent_encode [2048][768] ----
__global__ void __launch_bounds__(256) k_pool(const float* bert, const int* spans, const float* mask,
                                              short* entb) {
  int be = blockIdx.x;               // b*64+e
  int b = be >> 6;
  int u = spans[be * 2], v = spans[be * 2 + 1];
  float scale = mask[be] / (float)(v - u);
  const float* base = bert + (size_t)b * SEQ * D;
  for (int d = threadIdx.x; d < D; d += 256) {
    float s = 0.f;
    for (int t = u; t < v; ++t) s += base[t * D + d];
    entb[(size_t)be * D + d] = f2bf(s * scale);
  }
}

// ---- q/k GEMM: z=0 -> q (f32 out), z=1 -> k (bf16 out) ----
__global__ void __launch_bounds__(256) k_qk(const short* entb, const short* wqb, const short* wkb,
                                            const float* qbias, const float* kbias,
                                            float* qo, short* ko) {
  const int mblk = blockIdx.x, nblk = blockIdx.y;
  const short* W = blockIdx.z ? wkb : wqb;
  const float* bias = blockIdx.z ? kbias : qbias;
  __shared__ __align__(16) char lds[32768];
  const int tid = threadIdx.x, wid = tid >> 6, lane = tid & 63;
  const int wm = wid >> 1, wn = wid & 1;
  floatx4 acc[4][4] = {};
  const int m0 = mblk * 128, n0 = nblk * 128;
  for (int kt = 0; kt < 12; ++kt) {
    const int d0 = kt * 64;
    __syncthreads();
#pragma unroll
    for (int is = 0; is < 4; ++is) {
      int lin = (wid * 4 + is) * 64 + lane;
      int row = lin >> 3, slot = lin & 7;
      int cg = slot ^ (row & 7);
      gl_lds16(entb + (size_t)(m0 + row) * D + d0 + cg * 8, lds + lin * 16);
    }
#pragma unroll
    for (int is = 0; is < 4; ++is) {
      int lin = (wid * 4 + is) * 64 + lane;
      int row = lin >> 3, slot = lin & 7;
      int cg = slot ^ (row & 7);
      gl_lds16(W + (size_t)(n0 + row) * D + d0 + cg * 8, lds + 16384 + lin * 16);
    }
    __syncthreads();
#pragma unroll
    for (int ks = 0; ks < 2; ++ks) {
      int kc = ks * 4 + (lane >> 4);
      short8 af[4], bf_[4];
#pragma unroll
      for (int m = 0; m < 4; ++m) {
        int row = wm * 64 + m * 16 + (lane & 15);
        af[m] = *(const short8*)(lds + row * 128 + ((kc ^ (row & 7)) << 4));
      }
#pragma unroll
      for (int n = 0; n < 4; ++n) {
        int row = wn * 64 + n * 16 + (lane & 15);
        bf_[n] = *(const short8*)(lds + 16384 + row * 128 + ((kc ^ (row & 7)) << 4));
      }
#pragma unroll
      for (int m = 0; m < 4; ++m)
#pragma unroll
        for (int n = 0; n < 4; ++n)
          acc[m][n] = __builtin_amdgcn_mfma_f32_16x16x32_bf16(af[m], bf_[n], acc[m][n], 0, 0, 0);
    }
  }
#pragma unroll
  for (int m = 0; m < 4; ++m)
#pragma unroll
    for (int rg = 0; rg < 4; ++rg) {
      int r = m0 + wm * 64 + m * 16 + ((lane >> 4) << 2) + rg;
#pragma unroll
      for (int n = 0; n < 4; ++n) {
        int c = n0 + wn * 64 + n * 16 + (lane & 15);
        float v = acc[m][n][rg] + bias[c];
        if (blockIdx.z) ko[(size_t)r * D + c] = f2bf(v);
        else            qo[(size_t)r * D + c] = v;
      }
    }
}

// ---- main fused kernel ----
// LDS map (43008 B -> 3 blocks/CU):
//   0     : A tile (ln1) bf16 [128][8 x 16B chunks], swizzled   16384
//   16384 : H tile       bf16 [128][8 chunks], swizzled         16384
//   32768 : k bf16 [64][8 chunks], swizzled                      8192
//   40960 : lnoT bf16 [128][8]  ([e][7] = ln1_b[e])              2048
// 2 barriers/kt; A-stage hidden under H-gen, k-stage hidden under MFMA.
__global__ void __launch_bounds__(256, 3) k_main(const short* w1b, const float* qw, const short* kb,
                                                 const float* l1bias, const float* lno_w,
                                                 float* partial) {
  const int pblk = blockIdx.x, eblk = blockIdx.y;
  const int p0 = pblk * 128, e0 = eblk * 128;
  const int b = p0 >> 12, i0 = (p0 >> 6) & 63;
  __shared__ __align__(16) char lds[43008];
  const int tid = threadIdx.x, wid = tid >> 6, lane = tid & 63;
  const int wm = wid >> 1, wn = wid & 1;

  short* lnoT = (short*)(lds + 40960);  // [128][8] bf16, slot 7 = ln1 bias
  for (int idx = tid; idx < 1024; idx += 256) {
    int e = idx >> 3, r = idx & 7;
    float v = (r < NREL) ? lno_w[r * D + e0 + e] : l1bias[e0 + e];
    lnoT[idx] = f2bf(v);
  }

  const float* qbase = qw + (size_t)(b * NE + i0) * D;
  const short* kbase = kb + (size_t)(b * NE) * D;
  const int j2 = tid >> 2, dg = tid & 3;   // phase-2 mapping

  floatx4 acc[4][4] = {};

  // prologue: stage k for kt=0
#pragma unroll
  for (int is = 0; is < 2; ++is) {
    int c = is * 256 + tid;
    int row = c >> 3, sl = c & 7;
    int cg = sl ^ (row & 7);
    gl_lds16(kbase + (size_t)row * D + cg * 8, lds + 32768 + c * 16);
  }
  __syncthreads();

  for (int kt = 0; kt < 12; ++kt) {
    const int d0 = kt * 64;
    // ---- phase 2: issue A-stage (hidden); H = relu(q_i + k_j) ----
#pragma unroll
    for (int is = 0; is < 4; ++is) {
      int c = is * 256 + tid;
      int row = c >> 3, sl = c & 7;
      int cg = sl ^ (row & 7);
      gl_lds16(w1b + (size_t)(e0 + row) * D + d0 + cg * 8, lds + c * 16);
    }
    // k: 2 b128 reads (16 d, bf16), unpack once
    short8 kv0 = *(const short8*)(lds + 32768 + j2 * 128 + ((((dg * 2)) ^ (j2 & 7)) << 4));
    short8 kv1 = *(const short8*)(lds + 32768 + j2 * 128 + ((((dg * 2 + 1)) ^ (j2 & 7)) << 4));
    union { short8 s; unsigned u[4]; } K0, K1;
    K0.s = kv0; K1.s = kv1;
    float kf[16];
#pragma unroll
    for (int t = 0; t < 4; ++t) {
      kf[2 * t]     = __uint_as_float(K0.u[t] << 16);
      kf[2 * t + 1] = __uint_as_float(K0.u[t] & 0xFFFF0000u);
      kf[8 + 2 * t]     = __uint_as_float(K1.u[t] << 16);
      kf[8 + 2 * t + 1] = __uint_as_float(K1.u[t] & 0xFFFF0000u);
    }
#pragma unroll
    for (int r = 0; r < 2; ++r) {
      const float* qp = qbase + (size_t)r * D + d0 + dg * 16;
      floatx4 qa = *(const floatx4*)(qp);
      floatx4 qb2 = *(const floatx4*)(qp + 4);
      floatx4 qc = *(const floatx4*)(qp + 8);
      floatx4 qd = *(const floatx4*)(qp + 12);
      float qf[16];
#pragma unroll
      for (int t = 0; t < 4; ++t) {
        qf[t] = qa[t]; qf[4 + t] = qb2[t]; qf[8 + t] = qc[t]; qf[12 + t] = qd[t];
      }
      unsigned w[8];
#pragma unroll
      for (int t = 0; t < 8; ++t) {
        float lo = qf[2 * t] + kf[2 * t];
        float hi = qf[2 * t + 1] + kf[2 * t + 1];
        unsigned cw, rw;
        asm("v_cvt_pk_bf16_f32 %0, %1, %2" : "=v"(cw) : "v"(lo), "v"(hi));
        asm("v_pk_max_i16 %0, %1, 0" : "=v"(rw) : "v"(cw));
        w[t] = rw;
      }
      int hrow = r * 64 + j2;
      union { unsigned u[4]; short8 s; } W0, W1;
      W0.u[0] = w[0]; W0.u[1] = w[1]; W0.u[2] = w[2]; W0.u[3] = w[3];
      W1.u[0] = w[4]; W1.u[1] = w[5]; W1.u[2] = w[6]; W1.u[3] = w[7];
      *(short8*)(lds + 16384 + hrow * 128 + (((dg * 2) ^ (j2 & 7)) << 4)) = W0.s;
      *(short8*)(lds + 16384 + hrow * 128 + (((dg * 2 + 1) ^ (j2 & 7)) << 4)) = W1.s;
    }
    __syncthreads();   // A staged + H visible
    // ---- phase 3: issue k-stage for kt+1 (hidden); MFMA ----
    if (kt < 11) {
      const int d1 = d0 + 64;
#pragma unroll
      for (int is = 0; is < 2; ++is) {
        int c = is * 256 + tid;
        int row = c >> 3, sl = c & 7;
        int cg = sl ^ (row & 7);
        gl_lds16(kbase + (size_t)row * D + d1 + cg * 8, lds + 32768 + c * 16);
      }
    }
#pragma unroll
    for (int ks = 0; ks < 2; ++ks) {
      int kc = ks * 4 + (lane >> 4);
      short8 af[4], bf_[4];
#pragma unroll
      for (int m = 0; m < 4; ++m) {
        int row = wm * 64 + m * 16 + (lane & 15);
        af[m] = *(const short8*)(lds + row * 128 + ((kc ^ (row & 7)) << 4));
      }
#pragma unroll
      for (int n = 0; n < 4; ++n) {
        int row = wn * 64 + n * 16 + (lane & 15);
        bf_[n] = *(const short8*)(lds + 16384 + row * 128 + ((kc ^ (row & 7)) << 4));
      }
#pragma unroll
      for (int m = 0; m < 4; ++m)
#pragma unroll
        for (int n = 0; n < 4; ++n)
          acc[m][n] = __builtin_amdgcn_mfma_f32_16x16x32_bf16(af[m], bf_[n], acc[m][n], 0, 0, 0);
    }
    __syncthreads();   // k(kt+1) ready; A/H safe to overwrite
  }

  // stage 2: t = relu(acc + b1[e]); pr[n][r] += t * lno_w[r,e]; reduce over e
  float pr[4][NREL];
#pragma unroll
  for (int n = 0; n < 4; ++n)
#pragma unroll
    for (int r = 0; r < NREL; ++r) pr[n][r] = 0.f;
#pragma unroll
  for (int m = 0; m < 4; ++m)
#pragma unroll
    for (int rg = 0; rg < 4; ++rg) {
      int el = wm * 64 + m * 16 + ((lane >> 4) << 2) + rg;
      short8 wv = *(const short8*)(lnoT + el * 8);
      float w0 = __uint_as_float(((unsigned)(unsigned short)wv[0]) << 16);
      float w1 = __uint_as_float(((unsigned)(unsigned short)wv[1]) << 16);
      float w2 = __uint_as_float(((unsigned)(unsigned short)wv[2]) << 16);
      float w3 = __uint_as_float(((unsigned)(unsigned short)wv[3]) << 16);
      float w4 = __uint_as_float(((unsigned)(unsigned short)wv[4]) << 16);
      float w5 = __uint_as_float(((unsigned)(unsigned short)wv[5]) << 16);
      float w6 = __uint_as_float(((unsigned)(unsigned short)wv[6]) << 16);
      float bias = __uint_as_float(((unsigned)(unsigned short)wv[7]) << 16);
#pragma unroll
      for (int n = 0; n < 4; ++n) {
        float t = fmaxf(acc[m][n][rg] + bias, 0.f);
        pr[n][0] += t * w0; pr[n][1] += t * w1; pr[n][2] += t * w2; pr[n][3] += t * w3;
        pr[n][4] += t * w4; pr[n][5] += t * w5; pr[n][6] += t * w6;
      }
    }
#pragma unroll
  for (int n = 0; n < 4; ++n)
#pragma unroll
    for (int r = 0; r < NREL; ++r) {
      float v = pr[n][r];
      v += __shfl_xor(v, 16);
      v += __shfl_xor(v, 32);
      pr[n][r] = v;
    }

  // cross-wm merge via LDS, then plain vectorized partial stores (no atomics)
  __syncthreads();
  float* red = (float*)lds;  // [2 wn][4 n][16 lane][8]
  if (wm == 1 && (lane >> 4) == 0) {
#pragma unroll
    for (int n = 0; n < 4; ++n) {
      float* dst = red + ((wn * 4 + n) * 16 + lane) * 8;
#pragma unroll
      for (int r = 0; r < NREL; ++r) dst[r] = pr[n][r];
    }
  }
  __syncthreads();
  if (wm == 0 && (lane >> 4) == 0) {
#pragma unroll
    for (int n = 0; n < 4; ++n) {
      const float* src = red + ((wn * 4 + n) * 16 + lane) * 8;
      int plc = wn * 64 + n * 16 + lane;
      int pg = p0 + plc;
      float4 o0, o1;
      o0.x = pr[n][0] + src[0]; o0.y = pr[n][1] + src[1];
      o0.z = pr[n][2] + src[2]; o0.w = pr[n][3] + src[3];
      o1.x = pr[n][4] + src[4]; o1.y = pr[n][5] + src[5];
      o1.z = pr[n][6] + src[6]; o1.w = 0.f;
      float4* dst = (float4*)(partial + ((size_t)eblk * NPAIR + pg) * 8);
      dst[0] = o0; dst[1] = o1;
    }
  }
}

// ---- final reduce over 6 e-blocks + bias + mask ----
__global__ void __launch_bounds__(256) k_reduce(const float* partial, const float* lno_b,
                                                const float* mask, float* out) {
  int pg = blockIdx.x * 256 + threadIdx.x;
  float s[7] = {0.f, 0.f, 0.f, 0.f, 0.f, 0.f, 0.f};
#pragma unroll
  for (int e = 0; e < NEB; ++e) {
    const float4* p = (const float4*)(partial + ((size_t)e * NPAIR + pg) * 8);
    float4 x0 = p[0], x1 = p[1];
    s[0] += x0.x; s[1] += x0.y; s[2] += x0.z; s[3] += x0.w;
    s[4] += x1.x; s[5] += x1.y; s[6] += x1.z;
  }
  int jj = pg & 63, ii = (pg >> 6) & 63, bb = pg >> 12;
  float f = mask[bb * NE + ii] * mask[bb * NE + jj];
#pragma unroll
  for (int r = 0; r < NREL; ++r) out[(size_t)pg * NREL + r] = (s[r] + lno_b[r]) * f;
}

extern "C" void kernel_launch(void* const* d_in, const int* in_sizes, int n_in,
                              void* d_out, int out_size, void* d_ws, size_t ws_size,
                              hipStream_t stream) {
  const float* bert = (const float*)d_in[0];
  const int* spans = (const int*)d_in[1];
  const float* mask = (const float*)d_in[2];
  const float* wq_w = (const float*)d_in[3];
  const float* wq_b = (const float*)d_in[4];
  const float* wk_w = (const float*)d_in[5];
  const float* wk_b = (const float*)d_in[6];
  const float* ln1_w = (const float*)d_in[7];
  const float* ln1_b = (const float*)d_in[8];
  const float* lno_w = (const float*)d_in[9];
  const float* lno_b = (const float*)d_in[10];
  float* out = (float*)d_out;
  char* ws = (char*)d_ws;

  short* entb  = (short*)(ws);                 // 2048*768*2 = 3145728
  short* wqb   = (short*)(ws + 3145728);       // 768*768*2
  short* wkb   = (short*)(ws + 4325376);
  short* ln1bf = (short*)(ws + 5505024);
  float* qw    = (float*)(ws + 6684672);       // q f32: 2048*768*4 = 6291456
  short* kbw   = (short*)(ws + 12976128);      // k bf16: 2048*768*2 = 3145728
  float* part  = (float*)(ws + 16121856);      // [6][131072][8] f32 = 25165824

  hipLaunchKernelGGL(k_convert, dim3(576), dim3(256), 0, stream, wq_w, wk_w, ln1_w, wqb, wkb, ln1bf);
  hipLaunchKernelGGL(k_pool, dim3(BSZ * NE), dim3(256), 0, stream, bert, spans, mask, entb);
  hipLaunchKernelGGL(k_qk, dim3(16, 6, 2), dim3(256), 0, stream, entb, wqb, wkb, wq_b, wk_b, qw, kbw);
  hipLaunchKernelGGL(k_main, dim3(1024, NEB), dim3(256), 0, stream, ln1bf, qw, kbw, ln1_b, lno_w, part);
  hipLaunchKernelGGL(k_reduce, dim3(NPAIR / 256), dim3(256), 0, stream, part, lno_b, mask, out);
}

// Round 10
// 351.032 us; speedup vs baseline: 1.1108x; 1.1108x over previous
//
#include <hip/hip_runtime.h>
#include <hip/hip_bf16.h>

#define D 768
#define NE 64
#define BSZ 32
#define SEQ 512
#define NREL 7
#define NPAIR 131072
#define NEB 6

typedef __attribute__((ext_vector_type(8))) short short8;
typedef __attribute__((ext_vector_type(4))) float floatx4;

__device__ __forceinline__ short f2bf(float x) {
  union { __hip_bfloat16 b; short s; } u;
  u.b = __float2bfloat16(x);
  return u.s;
}

__device__ __forceinline__ void gl_lds16(const void* g, void* l) {
  __builtin_amdgcn_global_load_lds(
      (const __attribute__((address_space(1))) void*)g,
      (__attribute__((address_space(3))) void*)l, 16, 0, 0);
}

// ---- fused: span mean-pool (blocks 0..2047) + weight convert (blocks 2048..2623) ----
__global__ void __launch_bounds__(256) k_prep(const float* bert, const int* spans, const float* mask,
                                              const float* wq, const float* wk, const float* ln1,
                                              short* entb, short* owq, short* owk, short* oln1) {
  if (blockIdx.x < BSZ * NE) {
    int be = blockIdx.x;               // b*64+e
    int b = be >> 6;
    int u = spans[be * 2], v = spans[be * 2 + 1];
    float scale = mask[be] / (float)(v - u);
    const float* base = bert + (size_t)b * SEQ * D;
    for (int d = threadIdx.x; d < D; d += 256) {
      float s = 0.f;
      for (int t = u; t < v; ++t) s += base[t * D + d];
      entb[(size_t)be * D + d] = f2bf(s * scale);
    }
  } else {
    int idx = ((blockIdx.x - BSZ * NE) * 256 + threadIdx.x) * 4;
    if (idx >= D * D) return;
    float4 a = *(const float4*)(wq + idx);
    float4 b = *(const float4*)(wk + idx);
    float4 c = *(const float4*)(ln1 + idx);
    owq[idx + 0] = f2bf(a.x); owq[idx + 1] = f2bf(a.y); owq[idx + 2] = f2bf(a.z); owq[idx + 3] = f2bf(a.w);
    owk[idx + 0] = f2bf(b.x); owk[idx + 1] = f2bf(b.y); owk[idx + 2] = f2bf(b.z); owk[idx + 3] = f2bf(b.w);
    oln1[idx + 0] = f2bf(c.x); oln1[idx + 1] = f2bf(c.y); oln1[idx + 2] = f2bf(c.z); oln1[idx + 3] = f2bf(c.w);
  }
}

// ---- q/k GEMM: [2048,768] x [768,768]^T, 128x128 tiles, bf16 MFMA; OUTPUT bf16 ----
__global__ void __launch_bounds__(256) k_qk(const short* entb, const short* wqb, const short* wkb,
                                            const float* qbias, const float* kbias,
                                            short* qo, short* ko) {
  const int mblk = blockIdx.x, nblk = blockIdx.y;
  const short* W = blockIdx.z ? wkb : wqb;
  const float* bias = blockIdx.z ? kbias : qbias;
  short* out = blockIdx.z ? ko : qo;
  __shared__ __align__(16) char lds[32768];
  const int tid = threadIdx.x, wid = tid >> 6, lane = tid & 63;
  const int wm = wid >> 1, wn = wid & 1;
  floatx4 acc[4][4] = {};
  const int m0 = mblk * 128, n0 = nblk * 128;
  for (int kt = 0; kt < 12; ++kt) {
    const int d0 = kt * 64;
    __syncthreads();
#pragma unroll
    for (int is = 0; is < 4; ++is) {
      int lin = (wid * 4 + is) * 64 + lane;
      int row = lin >> 3, slot = lin & 7;
      int cg = slot ^ (row & 7);
      gl_lds16(entb + (size_t)(m0 + row) * D + d0 + cg * 8, lds + lin * 16);
    }
#pragma unroll
    for (int is = 0; is < 4; ++is) {
      int lin = (wid * 4 + is) * 64 + lane;
      int row = lin >> 3, slot = lin & 7;
      int cg = slot ^ (row & 7);
      gl_lds16(W + (size_t)(n0 + row) * D + d0 + cg * 8, lds + 16384 + lin * 16);
    }
    __syncthreads();
#pragma unroll
    for (int ks = 0; ks < 2; ++ks) {
      int kc = ks * 4 + (lane >> 4);
      short8 af[4], bf_[4];
#pragma unroll
      for (int m = 0; m < 4; ++m) {
        int row = wm * 64 + m * 16 + (lane & 15);
        af[m] = *(const short8*)(lds + row * 128 + ((kc ^ (row & 7)) << 4));
      }
#pragma unroll
      for (int n = 0; n < 4; ++n) {
        int row = wn * 64 + n * 16 + (lane & 15);
        bf_[n] = *(const short8*)(lds + 16384 + row * 128 + ((kc ^ (row & 7)) << 4));
      }
#pragma unroll
      for (int m = 0; m < 4; ++m)
#pragma unroll
        for (int n = 0; n < 4; ++n)
          acc[m][n] = __builtin_amdgcn_mfma_f32_16x16x32_bf16(af[m], bf_[n], acc[m][n], 0, 0, 0);
    }
  }
#pragma unroll
  for (int m = 0; m < 4; ++m)
#pragma unroll
    for (int rg = 0; rg < 4; ++rg) {
      int r = m0 + wm * 64 + m * 16 + ((lane >> 4) << 2) + rg;
#pragma unroll
      for (int n = 0; n < 4; ++n) {
        int c = n0 + wn * 64 + n * 16 + (lane & 15);
        out[(size_t)r * D + c] = f2bf(acc[m][n][rg] + bias[c]);
      }
    }
}

// ---- main fused kernel (R7 skeleton, HW-packed H-gen math) ----
// LDS map (43264 B total, 3 blocks/CU):
//   0     : A tile (ln1) bf16 [128][8 x 16B chunks], swizzled   16384
//   16384 : H tile       bf16 [128][8 chunks], swizzled         16384
//   32768 : kq bf16 [66][8 chunks] (0-63 = k rows, 64-65 = q)    8448
//   41216 : lnoT bf16 [128][8]  ([e][7] = ln1_b[e])              2048
__global__ void __launch_bounds__(256, 3) k_main(const short* w1b, const short* qb, const short* kb,
                                                 const float* l1bias, const float* lno_w,
                                                 float* partial) {
  const int pblk = blockIdx.x, eblk = blockIdx.y;
  const int p0 = pblk * 128, e0 = eblk * 128;
  const int b = p0 >> 12, i0 = (p0 >> 6) & 63;
  __shared__ __align__(16) char lds[43264];
  const int tid = threadIdx.x, wid = tid >> 6, lane = tid & 63;
  const int wm = wid >> 1, wn = wid & 1;

  short* lnoT = (short*)(lds + 41216);  // [128][8] bf16, slot 7 = ln1 bias
  for (int idx = tid; idx < 1024; idx += 256) {
    int e = idx >> 3, r = idx & 7;
    float v = (r < NREL) ? lno_w[r * D + e0 + e] : l1bias[e0 + e];
    lnoT[idx] = f2bf(v);
  }

  const int pl = tid >> 1;            // pair-local 0..127
  const int jj0 = pl & 63;
  const int qrow = 64 + (pl >> 6);
  const short* qbase = qb + (size_t)(b * NE + i0) * D;
  const short* kbase = kb + (size_t)(b * NE) * D;
  const int dpart = (tid & 1) * 32;

  floatx4 acc[4][4] = {};
  for (int kt = 0; kt < 12; ++kt) {
    const int d0 = kt * 64;
    __syncthreads();
    // ---- phase 1: stage A (128x64) + k (64x64) + q (2x64), all bf16, coalesced ----
#pragma unroll
    for (int is = 0; is < 4; ++is) {
      int c = is * 256 + tid;
      int row = c >> 3, sl = c & 7;
      int cg = sl ^ (row & 7);
      gl_lds16(w1b + (size_t)(e0 + row) * D + d0 + cg * 8, lds + c * 16);
    }
#pragma unroll
    for (int is = 0; is < 2; ++is) {
      int c = is * 256 + tid;
      int row = c >> 3, sl = c & 7;
      int cg = sl ^ (row & 7);
      gl_lds16(kbase + (size_t)row * D + d0 + cg * 8, lds + 32768 + c * 16);
    }
    if (tid < 16) {
      int row = 64 + (tid >> 3), sl = tid & 7;
      int cg = sl ^ (row & 7);
      gl_lds16(qbase + (size_t)(row - 64) * D + d0 + cg * 8,
               lds + 32768 + (512 + tid) * 16);
    }
    __syncthreads();
    // ---- phase 2: H = relu(q_i + k_j): unpack + f32 add + HW cvt_pk + packed relu ----
#pragma unroll
    for (int c4 = 0; c4 < 4; ++c4) {
      int cd = (dpart >> 3) + c4;         // d-chunk 0..7
      short8 kv = *(const short8*)(lds + 32768 + jj0 * 128 + ((cd ^ (jj0 & 7)) << 4));
      short8 qv = *(const short8*)(lds + 32768 + qrow * 128 + ((cd ^ (qrow & 7)) << 4));
      union { short8 s; unsigned u[4]; } K, Q;
      K.s = kv; Q.s = qv;
      union { unsigned u[4]; short8 s; } hv;
#pragma unroll
      for (int t = 0; t < 4; ++t) {
        float klo = __uint_as_float(K.u[t] << 16);
        float khi = __uint_as_float(K.u[t] & 0xFFFF0000u);
        float qlo = __uint_as_float(Q.u[t] << 16);
        float qhi = __uint_as_float(Q.u[t] & 0xFFFF0000u);
        float lo = klo + qlo;
        float hi = khi + qhi;
        unsigned cw, rw;
        asm("v_cvt_pk_bf16_f32 %0, %1, %2" : "=v"(cw) : "v"(lo), "v"(hi));
        asm("v_pk_max_i16 %0, %1, 0" : "=v"(rw) : "v"(cw));
        hv.u[t] = rw;
      }
      int slot = cd ^ (pl & 7);
      *(short8*)(lds + 16384 + pl * 128 + (slot << 4)) = hv.s;
    }
    __syncthreads();
    // ---- phase 3: MFMA ----
#pragma unroll
    for (int ks = 0; ks < 2; ++ks) {
      int kc = ks * 4 + (lane >> 4);
      short8 af[4], bf_[4];
#pragma unroll
      for (int m = 0; m < 4; ++m) {
        int row = wm * 64 + m * 16 + (lane & 15);
        af[m] = *(const short8*)(lds + row * 128 + ((kc ^ (row & 7)) << 4));
      }
#pragma unroll
      for (int n = 0; n < 4; ++n) {
        int row = wn * 64 + n * 16 + (lane & 15);
        bf_[n] = *(const short8*)(lds + 16384 + row * 128 + ((kc ^ (row & 7)) << 4));
      }
#pragma unroll
      for (int m = 0; m < 4; ++m)
#pragma unroll
        for (int n = 0; n < 4; ++n)
          acc[m][n] = __builtin_amdgcn_mfma_f32_16x16x32_bf16(af[m], bf_[n], acc[m][n], 0, 0, 0);
    }
  }

  // stage 2: t = relu(acc + b1[e]); pr[n][r] += t * lno_w[r,e]; reduce over e
  float pr[4][NREL];
#pragma unroll
  for (int n = 0; n < 4; ++n)
#pragma unroll
    for (int r = 0; r < NREL; ++r) pr[n][r] = 0.f;
#pragma unroll
  for (int m = 0; m < 4; ++m)
#pragma unroll
    for (int rg = 0; rg < 4; ++rg) {
      int el = wm * 64 + m * 16 + ((lane >> 4) << 2) + rg;
      short8 wv = *(const short8*)(lnoT + el * 8);
      float w0 = __uint_as_float(((unsigned)(unsigned short)wv[0]) << 16);
      float w1 = __uint_as_float(((unsigned)(unsigned short)wv[1]) << 16);
      float w2 = __uint_as_float(((unsigned)(unsigned short)wv[2]) << 16);
      float w3 = __uint_as_float(((unsigned)(unsigned short)wv[3]) << 16);
      float w4 = __uint_as_float(((unsigned)(unsigned short)wv[4]) << 16);
      float w5 = __uint_as_float(((unsigned)(unsigned short)wv[5]) << 16);
      float w6 = __uint_as_float(((unsigned)(unsigned short)wv[6]) << 16);
      float bias = __uint_as_float(((unsigned)(unsigned short)wv[7]) << 16);
#pragma unroll
      for (int n = 0; n < 4; ++n) {
        float t = fmaxf(acc[m][n][rg] + bias, 0.f);
        pr[n][0] += t * w0; pr[n][1] += t * w1; pr[n][2] += t * w2; pr[n][3] += t * w3;
        pr[n][4] += t * w4; pr[n][5] += t * w5; pr[n][6] += t * w6;
      }
    }
#pragma unroll
  for (int n = 0; n < 4; ++n)
#pragma unroll
    for (int r = 0; r < NREL; ++r) {
      float v = pr[n][r];
      v += __shfl_xor(v, 16);
      v += __shfl_xor(v, 32);
      pr[n][r] = v;
    }

  // cross-wm merge via LDS, then plain vectorized partial stores (no atomics)
  __syncthreads();
  float* red = (float*)lds;  // [2 wn][4 n][16 lane][8]
  if (wm == 1 && (lane >> 4) == 0) {
#pragma unroll
    for (int n = 0; n < 4; ++n) {
      float* dst = red + ((wn * 4 + n) * 16 + lane) * 8;
#pragma unroll
      for (int r = 0; r < NREL; ++r) dst[r] = pr[n][r];
    }
  }
  __syncthreads();
  if (wm == 0 && (lane >> 4) == 0) {
#pragma unroll
    for (int n = 0; n < 4; ++n) {
      const float* src = red + ((wn * 4 + n) * 16 + lane) * 8;
      int plc = wn * 64 + n * 16 + lane;
      int pg = p0 + plc;
      float4 o0, o1;
      o0.x = pr[n][0] + src[0]; o0.y = pr[n][1] + src[1];
      o0.z = pr[n][2] + src[2]; o0.w = pr[n][3] + src[3];
      o1.x = pr[n][4] + src[4]; o1.y = pr[n][5] + src[5];
      o1.z = pr[n][6] + src[6]; o1.w = 0.f;
      float4* dst = (float4*)(partial + ((size_t)eblk * NPAIR + pg) * 8);
      dst[0] = o0; dst[1] = o1;
    }
  }
}

// ---- final reduce over 6 e-blocks + bias + mask ----
__global__ void __launch_bounds__(256) k_reduce(const float* partial, const float* lno_b,
                                                const float* mask, float* out) {
  int pg = blockIdx.x * 256 + threadIdx.x;
  float s[7] = {0.f, 0.f, 0.f, 0.f, 0.f, 0.f, 0.f};
#pragma unroll
  for (int e = 0; e < NEB; ++e) {
    const float4* p = (const float4*)(partial + ((size_t)e * NPAIR + pg) * 8);
    float4 x0 = p[0], x1 = p[1];
    s[0] += x0.x; s[1] += x0.y; s[2] += x0.z; s[3] += x0.w;
    s[4] += x1.x; s[5] += x1.y; s[6] += x1.z;
  }
  int jj = pg & 63, ii = (pg >> 6) & 63, bb = pg >> 12;
  float f = mask[bb * NE + ii] * mask[bb * NE + jj];
#pragma unroll
  for (int r = 0; r < NREL; ++r) out[(size_t)pg * NREL + r] = (s[r] + lno_b[r]) * f;
}

extern "C" void kernel_launch(void* const* d_in, const int* in_sizes, int n_in,
                              void* d_out, int out_size, void* d_ws, size_t ws_size,
                              hipStream_t stream) {
  const float* bert = (const float*)d_in[0];
  const int* spans = (const int*)d_in[1];
  const float* mask = (const float*)d_in[2];
  const float* wq_w = (const float*)d_in[3];
  const float* wq_b = (const float*)d_in[4];
  const float* wk_w = (const float*)d_in[5];
  const float* wk_b = (const float*)d_in[6];
  const float* ln1_w = (const float*)d_in[7];
  const float* ln1_b = (const float*)d_in[8];
  const float* lno_w = (const float*)d_in[9];
  const float* lno_b = (const float*)d_in[10];
  float* out = (float*)d_out;
  char* ws = (char*)d_ws;

  short* entb  = (short*)(ws);                 // 2048*768*2 = 3145728
  short* wqb   = (short*)(ws + 3145728);       // 768*768*2
  short* wkb   = (short*)(ws + 4325376);
  short* ln1bf = (short*)(ws + 5505024);
  short* qbw   = (short*)(ws + 6684672);       // 2048*768*2 bf16
  short* kbw   = (short*)(ws + 9830400);
  float* part  = (float*)(ws + 12976128);      // [6][131072][8] f32 = 25165824

  hipLaunchKernelGGL(k_prep, dim3(BSZ * NE + 576), dim3(256), 0, stream,
                     bert, spans, mask, wq_w, wk_w, ln1_w, entb, wqb, wkb, ln1bf);
  hipLaunchKernelGGL(k_qk, dim3(16, 6, 2), dim3(256), 0, stream, entb, wqb, wkb, wq_b, wk_b, qbw, kbw);
  hipLaunchKernelGGL(k_main, dim3(1024, NEB), dim3(256), 0, stream, ln1bf, qbw, kbw, ln1_b, lno_w, part);
  hipLaunchKernelGGL(k_reduce, dim3(NPAIR / 256), dim3(256), 0, stream, part, lno_b, mask, out);
}